// Round 8
// baseline (215.541 us; speedup 1.0000x reference)
//
#include <hip/hip_runtime.h>
#include <stdint.h>

#define F 256
#define R 64                    // rows per block
#define THREADS 256
#define NCH 8                   // K-chunks (32 features each)
#define CH_SLOTS 1024           // 16B slots per chunk
#define NBUF 3                  // LDS buffers (depth-2 prefetch, counted vmcnt)

typedef __attribute__((ext_vector_type(8))) short short8;
typedef __attribute__((ext_vector_type(4))) float floatx4;

// Single-instruction rotate: alignbit(x,x,32-d) == rotl(x,d).
__device__ __forceinline__ uint32_t rotl32(uint32_t x, int d) {
  return __builtin_amdgcn_alignbit(x, x, (uint32_t)(32 - d));
}

// Threefry keys + hoisted round-injection constants (verified R0-R6).
struct TFK { uint32_t k0, k1, k2, a1, a2, a3, a4, a5; };

__device__ __forceinline__ TFK mkkeys(uint32_t k0, uint32_t k1) {
  TFK K;
  K.k0 = k0; K.k1 = k1; K.k2 = k0 ^ k1 ^ 0x1BD11BDAu;
  K.a1 = K.k2 + 1u; K.a2 = k0 + 2u; K.a3 = k1 + 3u;
  K.a4 = K.k2 + 4u; K.a5 = k0 + 5u;
  return K;
}

// Single-chain threefry2x32 (20 rounds) — fold_in, once per thread.
__device__ __forceinline__ void tf_one(const TFK& K, uint32_t& x0, uint32_t& x1) {
  x0 += K.k0; x1 += K.k1;
#define TF1(r) x0 += x1; x1 = rotl32(x1, r); x1 ^= x0;
  TF1(13) TF1(15) TF1(26) TF1(6)   x0 += K.k1; x1 += K.a1;
  TF1(17) TF1(29) TF1(16) TF1(24)  x0 += K.k2; x1 += K.a2;
  TF1(13) TF1(15) TF1(26) TF1(6)   x0 += K.k0; x1 += K.a3;
  TF1(17) TF1(29) TF1(16) TF1(24)  x0 += K.k1; x1 += K.a4;
  TF1(13) TF1(15) TF1(26) TF1(6)   x0 += K.k2; x1 += K.a5;
#undef TF1
}

// Dual-chain threefry: counters i, i+1 in manually interleaved lockstep.
__device__ __forceinline__ void tf_pair(const TFK& K, uint32_t i,
                                        uint32_t& oa, uint32_t& ob) {
  uint32_t a0 = K.k0, a1 = K.k1 + i;
  uint32_t b0 = K.k0, b1 = K.k1 + i + 1u;
#define TF2(r)  a0 += a1; b0 += b1;                         \
                a1 = rotl32(a1, r); b1 = rotl32(b1, r);     \
                a1 ^= a0; b1 ^= b0;
#define INJ2(u, v) a0 += (u); b0 += (u); a1 += (v); b1 += (v);
  TF2(13) TF2(15) TF2(26) TF2(6)   INJ2(K.k1, K.a1)
  TF2(17) TF2(29) TF2(16) TF2(24)  INJ2(K.k2, K.a2)
  TF2(13) TF2(15) TF2(26) TF2(6)   INJ2(K.k0, K.a3)
  TF2(17) TF2(29) TF2(16) TF2(24)  INJ2(K.k1, K.a4)
  TF2(13) TF2(15) TF2(26) TF2(6)   INJ2(K.k2, K.a5)
#undef TF2
#undef INJ2
  oa = a0 ^ a1;
  ob = b0 ^ b1;
}

// Two features (counters i, i+1) -> packed bf16 pair. Bit-identical numerics:
// 2.3283064365386963e-8 IS 100*2^-32 (do NOT multiply by 100 again), RNE
// round, v_perm pack == (ulo>>16)|((uhi>>16)<<16).
__device__ __forceinline__ uint32_t featpack(const TFK& K, uint32_t i) {
  uint32_t xa, xb;
  tf_pair(K, i, xa, xb);
  uint32_t ulo = __float_as_uint((float)xa * 2.3283064365386963e-8f);
  uint32_t uhi = __float_as_uint((float)xb * 2.3283064365386963e-8f);
  ulo += 0x7FFFu + ((ulo >> 16) & 1u);
  uhi += 0x7FFFu + ((uhi >> 16) & 1u);
  return __builtin_amdgcn_perm(uhi, ulo, 0x07060302u);
}

// One A-fragment (8 features = 4 pairs) for features fb..fb+7.
__device__ __forceinline__ short8 quad(const TFK& K, uint32_t fb) {
  uint32_t w32[4];
  #pragma unroll
  for (int p = 0; p < 4; ++p) w32[p] = featpack(K, fb + 2u * p);
  union { uint32_t w[4]; short8 s; } u;
  u.w[0] = w32[0]; u.w[1] = w32[1]; u.w[2] = w32[2]; u.w[3] = w32[3];
  return u.s;
}

// fp32 -> bf16 RNE (conv kernel only)
__device__ __forceinline__ uint32_t f2bf(float f) {
  uint32_t u = __float_as_uint(f);
  u += 0x7FFFu + ((u >> 16) & 1u);
  return u >> 16;
}

__device__ __forceinline__ void gl_lds16(const void* gptr, void* lptr) {
  __builtin_amdgcn_global_load_lds(
      (const __attribute__((address_space(1))) uint32_t*)gptr,
      (__attribute__((address_space(3))) uint32_t*)lptr, 16, 0, 0);
}

// One-time: W fp32 -> bf16 TRANSPOSED into slot order — BYTE-IDENTICAL to the
// verified R0/R6 conv. Global slot S: GT=S>>10, C=(S>>5)&31, G5=S&31.
// Holds W[GT*32+G5][C*8 .. C*8+7] as 8 bf16.
__global__ __launch_bounds__(256) void femb_conv(const float* __restrict__ W,
                                                 uint16_t* __restrict__ ws) {
  int s = blockIdx.x * 256 + threadIdx.x;   // 8192 slots
  int gt = s >> 10;
  int c = (s >> 5) & 31;
  int g = s & 31;
  const float4* src = (const float4*)(W + (size_t)(gt * 32 + g) * F + c * 8);
  float4 v0 = src[0], v1 = src[1];
  short8 o;
  o[0] = (short)f2bf(v0.x); o[1] = (short)f2bf(v0.y);
  o[2] = (short)f2bf(v0.z); o[3] = (short)f2bf(v0.w);
  o[4] = (short)f2bf(v1.x); o[5] = (short)f2bf(v1.y);
  o[6] = (short)f2bf(v1.z); o[7] = (short)f2bf(v1.w);
  *(short8*)(ws + (size_t)s * 8) = o;
}

// DMA one K-chunk kt (features kt*32..+31, all 256 g-rows) into LDS.
// K-chunk kt occupies 8 runs of 128 contiguous slots in the VERIFIED global
// slot space: S = gt*1024 + kt*128 + r  (gt=0..7, r=0..127), because
// content(S) = W[gt*32+(S&31)][((S>>5)&31)*8] and we need C = kt*4 + (r>>5).
// Local slot L = gt*128 + r  ->  S(L) = (L>>7)*1024 + kt*128 + (L&127).
// Per wave-instruction, the 64 lanes lie inside one 128-run (L_base is a
// multiple of 64, gt = L_base>>7 constant) -> source linear in lane, 1 KiB
// contiguous, same codegen shape as the verified dma_chunk.
__device__ __forceinline__ void dma_kchunk(const uint16_t* __restrict__ Wbf,
                                           int kt, uint16_t* dst,
                                           int wave, int lane) {
  #pragma unroll
  for (int it = 0; it < CH_SLOTS / THREADS; ++it) {
    int Lb = it * THREADS + wave * 64;            // wave-uniform, multiple of 64
    const uint16_t* g = Wbf +
        (size_t)((Lb >> 7) * 8192 + kt * 1024 + (Lb & 127) * 8);
    gl_lds16(g + (size_t)lane * 8, dst + (size_t)Lb * 8);
  }
}

// K-chunked main: chunk kt stages features kt*32..+31 for ALL 256 outputs and
// consumes ONLY afragC (the verified quad(K, kt*32+qd*8)). The quad for chunk
// kt+1 is computed inside chunk kt's body, one featpack per 4-MFMA quartet —
// ~1240 cyc of independent VALU laid over each chunk's ~300 cyc memory phase.
// Sync schedule, conv layout, A-frags, delivered W bytes, accumulation order,
// and store layout are all identical to the verified R6 kernel.
__global__ __launch_bounds__(THREADS, 3) void femb_main(
    const float* __restrict__ x, const uint16_t* __restrict__ Wbf,
    const float* __restrict__ bias, float* __restrict__ out) {
  __shared__ uint16_t sW[NBUF][CH_SLOTS * 8];   // 3 x 16 KB

  const int tid  = threadIdx.x;
  const int lane = tid & 63;
  const int wave = tid >> 6;
  const int qd   = lane >> 4;
  const int l16  = lane & 15;
  const size_t row0 = (size_t)blockIdx.x * R;
  const int myrow = (int)row0 + wave * 16 + l16;

  // x and bias first: at the loop-top vmcnt(4) they are older than DMA(1),
  // so the count drains {x, bias, DMA(0)} and leaves DMA(1) in flight.
  float xv = x[myrow];
  float bgv[16];
  #pragma unroll
  for (int n = 0; n < 16; ++n) bgv[n] = bias[n * 16 + l16];

  // Prefetch K-chunks 0 and 1 — hidden under fold_in + quad 0 (~2K cycles).
  dma_kchunk(Wbf, 0, sW[0], wave, lane);
  dma_kchunk(Wbf, 1, sW[1], wave, lane);

  // fold_in: key = threefry((0,42), (0, bitcast(x))). 4x redundant across qd.
  const TFK K42 = mkkeys(0u, 42u);
  uint32_t u0 = 0u, u1 = __float_as_uint(xv);
  tf_one(K42, u0, u1);
  const TFK K = mkkeys(u0, u1);

  // A-fragment for chunk 0: lane (qd,l16) owns A[m=l16][k=qd*8+j],
  // features kt*32+qd*8+j for row wave*16+l16 (verified mapping).
  short8 afragC = quad(K, (uint32_t)(qd * 8));

  floatx4 acc[16];
  #pragma unroll
  for (int n = 0; n < 16; ++n) acc[n] = (floatx4){0.f, 0.f, 0.f, 0.f};

  #pragma unroll 1
  for (int kt = 0; kt < NCH; ++kt) {
    // Counted wait: 4 loads/wave/chunk. Drains chunk kt's DMA (+prologue
    // x/bias at kt=0), leaves chunk kt+1's 4 loads in flight (verified R6
    // schedule). Last iter: nothing newer outstanding -> vmcnt(0).
    __builtin_amdgcn_sched_barrier(0);
    if (kt == NCH - 1)
      asm volatile("s_waitcnt vmcnt(0) lgkmcnt(0)" ::: "memory");
    else
      asm volatile("s_waitcnt vmcnt(4) lgkmcnt(0)" ::: "memory");
    __builtin_amdgcn_s_barrier();
    __builtin_amdgcn_sched_barrier(0);

    // DMA chunk kt+2 into buf (kt+2)%3: its previous readers synced at the
    // barrier above; (kt, kt+1, kt+2) mod 3 are distinct.
    if (kt + 2 < NCH)
      dma_kchunk(Wbf, kt + 2, sW[(kt + 2) % NBUF], wave, lane);

    // Read local slot L = (n2>>1)*128 + qd*32 + (n2&1)*16 + l16:
    // content = W[n2*16+l16][(kt*4+qd)*8 ..+7] — byte-identical delivery to
    // R6's verified read. uint16 offset = L*8.
    const uint16_t* bp = &sW[kt % NBUF][(size_t)(qd * 256 + l16 * 8)];
    const uint32_t fb = (uint32_t)((kt + 1) * 32 + qd * 8);
    const bool more = (kt + 1 < NCH);
    uint32_t w32[4];

    #pragma unroll
    for (int q = 0; q < 4; ++q) {
      #pragma unroll
      for (int h = 0; h < 4; ++h) {
        int n2 = q * 4 + h;
        short8 b = *(const short8*)(bp + (n2 >> 1) * 1024 + (n2 & 1) * 128);
        acc[n2] = __builtin_amdgcn_mfma_f32_16x16x32_bf16(afragC, b, acc[n2],
                                                          0, 0, 0);
      }
      // One featpack (2 features, ~310 instrs) per MFMA quartet: independent
      // VALU the scheduler can slot under the ds_read/MFMA waits.
      if (more) w32[q] = featpack(K, fb + 2u * q);
    }

    if (more) {
      union { uint32_t w[4]; short8 s; } u;
      u.w[0] = w32[0]; u.w[1] = w32[1]; u.w[2] = w32[2]; u.w[3] = w32[3];
      afragC = u.s;
    }
  }

  // Epilogue: D[row=qd*4+reg][col=l16] (m89-verified layout), one burst.
  // acc[n2] holds g = n2*16 + l16 — identical to R6's store mapping.
  const size_t growbase = row0 + (size_t)(wave * 16 + qd * 4);
  #pragma unroll
  for (int n = 0; n < 16; ++n) {
    int g = n * 16 + l16;
    #pragma unroll
    for (int reg = 0; reg < 4; ++reg)
      out[(growbase + reg) * F + g] = acc[n][reg] + bgv[n];
  }
}

extern "C" void kernel_launch(void* const* d_in, const int* in_sizes, int n_in,
                              void* d_out, int out_size, void* d_ws, size_t ws_size,
                              hipStream_t stream) {
  const float* x = (const float*)d_in[0];
  const float* W = (const float*)d_in[1];
  const float* b = (const float*)d_in[2];
  float* out = (float*)d_out;
  uint16_t* wsbf = (uint16_t*)d_ws;          // 128 KB of ws_size
  const int nrows = in_sizes[0];             // 131072
  const int blocks = nrows / R;              // 2048

  hipLaunchKernelGGL(femb_conv, dim3((F * F / 8) / 256), dim3(256), 0, stream, W, wsbf);
  hipLaunchKernelGGL(femb_main, dim3(blocks), dim3(THREADS), 0, stream,
                     x, wsbf, b, out);
}